// Round 16
// baseline (190.125 us; speedup 1.0000x reference)
//
#include <hip/hip_runtime.h>
#include <hip/hip_bf16.h>

// Problem: B=8, N=2048, C=320, H=5, D=64, SCALE=1/8. Inputs f32, output f32.
// out = proj( softmax(Q K^T / 8) V ), qkv = x @ w_qkv^T (w stored [out,in]).
// ROUND 16: attn computes S^T = K*Q^T (operands swapped; fragment layouts are
// lane-symmetric so loads unchanged). The C-layout of S^T per lane
// (P^T[n=quad*4+r][m=col]) IS the B-operand layout of mfma_f32_16x16x16_bf16
// (k=quad*4+j), so exp2 output packs in-register and feeds PV directly:
// NO LDS stores / fence / reads in the K-loop. V' re-laid-out for K=16 frags.
// TOOLCHAIN RULES: (1) rounds 7 & 9 — ANY min-occupancy hint clamps attn to
// the 64-VGPR tier and spills. Allocator must float. (2) round 15 — never
// gate __builtin_amdgcn_* with __has_builtin (false on HIP host pass); call
// builtins bare.

typedef __attribute__((ext_vector_type(8))) short bf16x8;   // 8 bf16 = 4 VGPRs
typedef __attribute__((ext_vector_type(4))) short bf16x4;   // 4 bf16 = 2 VGPRs
typedef __attribute__((ext_vector_type(4))) float f32x4;

#define MFMA(a, b, c)   __builtin_amdgcn_mfma_f32_16x16x32_bf16((a), (b), (c), 0, 0, 0)
#define MFMA16(a, b, c) __builtin_amdgcn_mfma_f32_16x16x16bf16_1k((a), (b), (c), 0, 0, 0)

// Q pre-scale: (1/8) * log2(e)
#define QSCALE 0.18033688322643216f

static __device__ inline bf16x8 ld8(const __hip_bfloat16* p) {
    return *reinterpret_cast<const bf16x8*>(p);
}

// fast f32->bf16: exact RNE for all FINITE values (pipeline is NaN-free).
static __device__ inline unsigned short bfbits(float v) {
    unsigned int u = __builtin_bit_cast(unsigned int, v);
    u += 0x7FFFu + ((u >> 16) & 1u);
    return (unsigned short)(u >> 16);
}

// convert 8 consecutive f32 to a bf16x8 vector (fast pack)
static __device__ inline bf16x8 cvt8(const float* src) {
    float4 a = *reinterpret_cast<const float4*>(src);
    float4 b = *reinterpret_cast<const float4*>(src + 4);
    bf16x8 v;
    v[0] = (short)bfbits(a.x); v[1] = (short)bfbits(a.y);
    v[2] = (short)bfbits(a.z); v[3] = (short)bfbits(a.w);
    v[4] = (short)bfbits(b.x); v[5] = (short)bfbits(b.y);
    v[6] = (short)bfbits(b.z); v[7] = (short)bfbits(b.w);
    return v;
}

// ---------------------------------------------------------------------------
// Kernel 0: x f32 -> bf16 (x is re-read 15x by qkv; convert once).
// ---------------------------------------------------------------------------
__global__ __launch_bounds__(256)
void cvt_x(const float* __restrict__ x, __hip_bfloat16* __restrict__ xb)
{
    const size_t tid = (size_t)blockIdx.x * blockDim.x + threadIdx.x;
    const size_t stride = (size_t)gridDim.x * blockDim.x;
    const float4* x4 = (const float4*)x;
    ushort4* xb4 = (ushort4*)xb;
    for (size_t i = tid; i < 1310720u; i += stride) {   // 5242880/4
        float4 v = x4[i];
        ushort4 u;
        u.x = bfbits(v.x); u.y = bfbits(v.y);
        u.z = bfbits(v.z); u.w = bfbits(v.w);
        xb4[i] = u;
    }
}

// ---------------------------------------------------------------------------
// Kernel 1: QKV GEMM, plain bf16, BK=64. A = xb (bf16), B = w_qkv (inline cvt).
// Q written row-major [bh][n][d] PRE-SCALED by QSCALE.
// K in fragment order K' (K=32 frags, valid as A- or B-operand).
// V in K=16 A-fragment order V'16: elem(n,d) -> panel p=n>>6, n6=n&63,
//   frag f=(n6>>4)*4+(d>>4), lane=((n6>>2)&3)*16+(d&15), j=n6&3.
// ---------------------------------------------------------------------------
__global__ __launch_bounds__(256)
void qkv_kernel(const __hip_bfloat16* __restrict__ xb,
                const float* __restrict__ w,
                __hip_bfloat16* __restrict__ qout,
                __hip_bfloat16* __restrict__ kp,
                __hip_bfloat16* __restrict__ vp)
{
    __shared__ __align__(16) __hip_bfloat16 As[128 * 72];  // 128x64, pad->72
    __shared__ __align__(16) __hip_bfloat16 Bs[64 * 72];   // 64x64,  pad->72

    const int tid  = threadIdx.x;
    const int wv   = tid >> 6;
    const int lane = tid & 63;
    const int quad = lane >> 4;
    const int col  = lane & 15;
    const int m0   = blockIdx.x * 128;
    const int n0   = blockIdx.y * 64;

    f32x4 acc[2][4];
#pragma unroll
    for (int i = 0; i < 2; ++i)
#pragma unroll
        for (int j = 0; j < 4; ++j) acc[i][j] = (f32x4){0.f, 0.f, 0.f, 0.f};

    for (int k0 = 0; k0 < 320; k0 += 64) {
        __syncthreads();
#pragma unroll
        for (int i = 0; i < 4; ++i) {
            int ch = tid + i * 256;
            int r = ch >> 3, sg = ch & 7;
            *reinterpret_cast<float4*>(&As[r * 72 + sg * 8]) =
                *reinterpret_cast<const float4*>(&xb[(m0 + r) * 320 + k0 + sg * 8]);
        }
#pragma unroll
        for (int i = 0; i < 2; ++i) {
            int ch = tid + i * 256;
            int r = ch >> 3, sg = ch & 7;
            *reinterpret_cast<bf16x8*>(&Bs[r * 72 + sg * 8]) =
                cvt8(&w[(n0 + r) * 320 + k0 + sg * 8]);
        }
        __syncthreads();

#pragma unroll
        for (int hf = 0; hf < 2; ++hf) {
            bf16x8 a0 = ld8(&As[(wv * 32 + col) * 72 + hf * 32 + quad * 8]);
            bf16x8 a1 = ld8(&As[(wv * 32 + 16 + col) * 72 + hf * 32 + quad * 8]);
#pragma unroll
            for (int nt = 0; nt < 4; ++nt) {
                bf16x8 b = ld8(&Bs[(nt * 16 + col) * 72 + hf * 32 + quad * 8]);
                acc[0][nt] = MFMA(a0, b, acc[0][nt]);
                acc[1][nt] = MFMA(a1, b, acc[1][nt]);
            }
        }
    }

    const int s = blockIdx.y / 5;   // 0=Q,1=K,2=V
    const int h = blockIdx.y % 5;
    unsigned short* qo = (unsigned short*)qout;
    unsigned short* ko = (unsigned short*)kp;
    unsigned short* vo = (unsigned short*)vp;
#pragma unroll
    for (int mt = 0; mt < 2; ++mt) {
#pragma unroll
        for (int nt = 0; nt < 4; ++nt) {
#pragma unroll
            for (int r = 0; r < 4; ++r) {
                int m = m0 + wv * 32 + mt * 16 + quad * 4 + r;
                int d = nt * 16 + col;
                int b = m >> 11, n = m & 2047;
                int bh = b * 5 + h;
                float val = acc[mt][nt][r];
                if (s == 0) {
                    qo[((size_t)bh * 2048 + n) * 64 + d] = bfbits(val * QSCALE);
                } else if (s == 1) {
                    int p = n >> 6, nn = n & 63;
                    size_t a = ((size_t)(bh * 32 + p) * 8 + (d >> 5) * 4 + (nn >> 4)) * 512
                             + (((d >> 3) & 3) * 16 + (nn & 15)) * 8 + (d & 7);
                    ko[a] = bfbits(val);
                } else {
                    int p = n >> 6, n6 = n & 63;
                    size_t a = ((size_t)(bh * 32 + p) * 16 + (n6 >> 4) * 4 + (d >> 4)) * 256
                             + (((n6 >> 2) & 3) * 16 + (d & 15)) * 4 + (n6 & 3);
                    vo[a] = bfbits(val);
                }
            }
        }
    }
}

// ---------------------------------------------------------------------------
// Kernel 2: flash attention, S^T formulation — NO LDS in the K-loop.
// Per tile: S^T = K*Q^T (16 MFMA, operands swapped) -> exp2 -> in-register
// bf16x4 pack (= B-operand of mfma_16x16x16) -> PV (32 MFMA16).
// 2-wave KV-split, end-of-kernel LDS combine only.
// ---------------------------------------------------------------------------
__global__ __launch_bounds__(128)
void attn_kernel(const __hip_bfloat16* __restrict__ Q,
                 const __hip_bfloat16* __restrict__ Kp,
                 const __hip_bfloat16* __restrict__ Vp,
                 __hip_bfloat16* __restrict__ A2)
{
    __shared__ __align__(16) unsigned char smraw[8448];  // combine: 64x32 f32 + 32 f32

    const int tid  = threadIdx.x;
    const int wv   = tid >> 6;
    const int lane = tid & 63;
    const int quad = lane >> 4;
    const int col  = lane & 15;
    const int bh = blockIdx.y, b = bh / 5, h = bh % 5;
    const int q0 = blockIdx.x * 32;
    const int t0 = wv * 16;

    const __hip_bfloat16* kt = Kp + (size_t)bh * 131072 + (size_t)t0 * 4096 + lane * 8;
    const __hip_bfloat16* vt = Vp + (size_t)bh * 131072 + (size_t)t0 * 4096 + lane * 4;
    const __hip_bfloat16* Qh = Q + (size_t)bh * 131072;

    // Q fragments: rows q0+mt*16+col, k = hf*32+quad*8+j (valid as B-operand)
    bf16x8 qf[2][2];
#pragma unroll
    for (int mt = 0; mt < 2; ++mt)
#pragma unroll
        for (int hf = 0; hf < 2; ++hf)
            qf[mt][hf] = ld8(&Qh[(q0 + mt * 16 + col) * 64 + hf * 32 + quad * 8]);

    f32x4 lpv[2];
    f32x4 o[4][2];   // o^T[dt][mt]: lane holds o^T[d=dt*16+quad*4+r][m=mt*16+col]
#pragma unroll
    for (int mt = 0; mt < 2; ++mt) lpv[mt] = (f32x4){0.f, 0.f, 0.f, 0.f};
#pragma unroll
    for (int dt = 0; dt < 4; ++dt)
#pragma unroll
        for (int mt = 0; mt < 2; ++mt) o[dt][mt] = (f32x4){0.f, 0.f, 0.f, 0.f};

    // preload first K panel (K' works as A-operand: layouts lane-symmetric)
    bf16x8 ka[8];
#pragma unroll
    for (int f = 0; f < 8; ++f) ka[f] = ld8(kt + f * 512);
    kt += 4096;

    for (int t = 0; t < 16; ++t) {
        // S^T tiles: s[nt][mt]; lane: row n=nt*16+quad*4+r, col m=mt*16+col
        f32x4 s[4][2];
#pragma unroll
        for (int nt = 0; nt < 4; ++nt)
#pragma unroll
            for (int mt = 0; mt < 2; ++mt) {
                f32x4 z = (f32x4){0.f, 0.f, 0.f, 0.f};
                z = MFMA(ka[nt], qf[mt][0], z);
                z = MFMA(ka[4 + nt], qf[mt][1], z);
                s[nt][mt] = z;
            }

        // V'16 loads for THIS tile: frag f=nt*4+dt, one dwordx2 per lane
        bf16x4 va[16];
#pragma unroll
        for (int f = 0; f < 16; ++f)
            va[f] = *reinterpret_cast<const bf16x4*>(vt + f * 256);
        vt += 4096;

        // unconditional prefetch of next K panel (one-past lands in vp buffer)
#pragma unroll
        for (int f = 0; f < 8; ++f) ka[f] = ld8(kt + f * 512);
        kt += 4096;

        // softmax + PV, per nt: exp2 -> in-register pack -> 8 MFMA16
#pragma unroll
        for (int nt = 0; nt < 4; ++nt) {
#pragma unroll
            for (int mt = 0; mt < 2; ++mt) {
                f32x4 pv;
#pragma unroll
                for (int r = 0; r < 4; ++r)
                    pv[r] = __builtin_amdgcn_exp2f(s[nt][mt][r]);
                lpv[mt] += pv;
                bf16x4 pb;
#pragma unroll
                for (int r = 0; r < 4; ++r) pb[r] = (short)bfbits(pv[r]);
#pragma unroll
                for (int dt = 0; dt < 4; ++dt)
                    o[dt][mt] = MFMA16(va[nt * 4 + dt], pb, o[dt][mt]);
            }
        }
    }

    // l[m]: hadd within lane, then reduce across the 4 quad-lanes (xor 16, 32)
    float lsum[2];
#pragma unroll
    for (int mt = 0; mt < 2; ++mt) {
        float v = lpv[mt][0] + lpv[mt][1] + lpv[mt][2] + lpv[mt][3];
        v += __shfl_xor(v, 16, 64);
        v += __shfl_xor(v, 32, 64);
        lsum[mt] = v;
    }

    // combine the two KV-half partials through LDS
    float* cbo = (float*)smraw;        // [64 d][32 m]
    float* cbl = cbo + 2048;           // [32 m]
    __syncthreads();
    if (wv == 1) {
#pragma unroll
        for (int dt = 0; dt < 4; ++dt)
#pragma unroll
            for (int mt = 0; mt < 2; ++mt)
#pragma unroll
                for (int r = 0; r < 4; ++r)
                    cbo[(dt * 16 + quad * 4 + r) * 32 + mt * 16 + col] = o[dt][mt][r];
        if (quad == 0)
#pragma unroll
            for (int mt = 0; mt < 2; ++mt) cbl[mt * 16 + col] = lsum[mt];
    }
    __syncthreads();
    if (wv == 0) {
        unsigned short* a2o = (unsigned short*)A2;
#pragma unroll
        for (int mt = 0; mt < 2; ++mt) {
            float inv = 1.0f / (lsum[mt] + cbl[mt * 16 + col]);
            size_t rowbase = ((size_t)(b * 2048 + q0 + mt * 16 + col)) * 320 + h * 64;
#pragma unroll
            for (int dt = 0; dt < 4; ++dt)
#pragma unroll
                for (int r = 0; r < 4; ++r) {
                    int d = dt * 16 + quad * 4 + r;
                    float val = (o[dt][mt][r] + cbo[d * 32 + mt * 16 + col]) * inv;
                    a2o[rowbase + d] = bfbits(val);
                }
        }
    }
}

// ---------------------------------------------------------------------------
// Kernel 3: output projection, plain bf16, BK=64, inline w conversion.
// ---------------------------------------------------------------------------
__global__ __launch_bounds__(256)
void proj_kernel(const __hip_bfloat16* __restrict__ a2,
                 const float* __restrict__ w,
                 const float* __restrict__ bias,
                 float* __restrict__ out)
{
    __shared__ __align__(16) __hip_bfloat16 As[128 * 72];
    __shared__ __align__(16) __hip_bfloat16 Bs[64 * 72];

    const int tid  = threadIdx.x;
    const int wv   = tid >> 6;
    const int lane = tid & 63;
    const int quad = lane >> 4;
    const int col  = lane & 15;
    const int m0   = blockIdx.x * 128;
    const int n0   = blockIdx.y * 64;

    f32x4 acc[2][4];
#pragma unroll
    for (int i = 0; i < 2; ++i)
#pragma unroll
        for (int j = 0; j < 4; ++j) acc[i][j] = (f32x4){0.f, 0.f, 0.f, 0.f};

    for (int k0 = 0; k0 < 320; k0 += 64) {
        __syncthreads();
#pragma unroll
        for (int i = 0; i < 4; ++i) {
            int ch = tid + i * 256;
            int r = ch >> 3, sg = ch & 7;
            *reinterpret_cast<float4*>(&As[r * 72 + sg * 8]) =
                *reinterpret_cast<const float4*>(&a2[(m0 + r) * 320 + k0 + sg * 8]);
        }
#pragma unroll
        for (int i = 0; i < 2; ++i) {
            int ch = tid + i * 256;
            int r = ch >> 3, sg = ch & 7;
            *reinterpret_cast<bf16x8*>(&Bs[r * 72 + sg * 8]) =
                cvt8(&w[(n0 + r) * 320 + k0 + sg * 8]);
        }
        __syncthreads();

#pragma unroll
        for (int hf = 0; hf < 2; ++hf) {
            bf16x8 a0 = ld8(&As[(wv * 32 + col) * 72 + hf * 32 + quad * 8]);
            bf16x8 a1 = ld8(&As[(wv * 32 + 16 + col) * 72 + hf * 32 + quad * 8]);
#pragma unroll
            for (int nt = 0; nt < 4; ++nt) {
                bf16x8 b = ld8(&Bs[(nt * 16 + col) * 72 + hf * 32 + quad * 8]);
                acc[0][nt] = MFMA(a0, b, acc[0][nt]);
                acc[1][nt] = MFMA(a1, b, acc[1][nt]);
            }
        }
    }

#pragma unroll
    for (int nt = 0; nt < 4; ++nt) {
        float bv = bias[n0 + nt * 16 + col];
#pragma unroll
        for (int mt = 0; mt < 2; ++mt) {
#pragma unroll
            for (int r = 0; r < 4; ++r) {
                int m = m0 + wv * 32 + mt * 16 + quad * 4 + r;
                out[(size_t)m * 320 + n0 + nt * 16 + col] = acc[mt][nt][r] + bv;
            }
        }
    }
}

// ---------------------------------------------------------------------------
extern "C" void kernel_launch(void* const* d_in, const int* in_sizes, int n_in,
                              void* d_out, int out_size, void* d_ws, size_t ws_size,
                              hipStream_t stream)
{
    const float* x      = (const float*)d_in[0];  // [8,2048,320]
    const float* w_qkv  = (const float*)d_in[1];  // [960,320]
    const float* w_proj = (const float*)d_in[2];  // [320,320]
    const float* b_proj = (const float*)d_in[3];  // [320]
    float* out = (float*)d_out;                   // [8,2048,320] f32

    const size_t NX = 5242880;
    __hip_bfloat16* xb = (__hip_bfloat16*)d_ws;   // [B,N,C] bf16 (reused as a2)
    __hip_bfloat16* q  = xb + NX;                 // [bh][n][d], pre-scaled
    __hip_bfloat16* kp = q + NX;                  // K' fragment order
    __hip_bfloat16* vp = kp + NX;                 // V'16 fragment order (adjacent:
                                                  //  one-past K prefetch lands here)
    __hip_bfloat16* a2 = xb;                      // alias: xb dead after qkv

    cvt_x<<<1024, 256, 0, stream>>>(x, xb);
    qkv_kernel<<<dim3(128, 15), 256, 0, stream>>>(xb, w_qkv, q, kp, vp);
    attn_kernel<<<dim3(64, 40), 128, 0, stream>>>(q, kp, vp, a2);
    proj_kernel<<<dim3(128, 5), 256, 0, stream>>>(a2, w_proj, b_proj, out);
}